// Round 1
// baseline (29.568 us; speedup 1.0000x reference)
//
#include <hip/hip_runtime.h>

namespace {

constexpr int   R_  = 131072;
constexpr int   J_  = 64;
constexpr int   M_  = 32;
constexpr float DT_  = 0.1f;
constexpr float EPS_ = 1e-6f;

constexpr int ROWS    = 32;    // rows per block
constexpr int THREADS = 512;   // 8 waves; 16 lanes per row, 4 rows per wave

__global__ __launch_bounds__(THREADS)
void econ_kernel(const float* __restrict__ need_prev,
                 const float* __restrict__ inventory,    // [R][J]
                 const float* __restrict__ endowment,    // [R][J]
                 const float* __restrict__ price,        // [J][R]
                 const float* __restrict__ pool_atp,
                 const float* __restrict__ pool_adp,
                 const float* __restrict__ pool_amp,
                 const float* __restrict__ greed,
                 const float* __restrict__ innovation,   // [R][J]
                 const float* __restrict__ extraction_eff, // [R][M]
                 const float* __restrict__ deposits,       // [R][M]
                 const float* __restrict__ exergy_price,
                 const float* __restrict__ bases,         // [3]
                 const float* __restrict__ scales,        // [3]
                 float* __restrict__ out)                 // gdp[R], aec[R]
{
    __shared__ float prT[ROWS][J_ + 1];   // price tile transposed: [r_local][j]

    const int t  = threadIdx.x;
    const int r0 = blockIdx.x * ROWS;

    // ---- stage price tile (64 j x 32 r), coalesced float4 along r ----
    {
        const int j  = t >> 3;          // 0..63
        const int rq = (t & 7) * 4;     // 0,4,...,28
        const float4 p4 = *reinterpret_cast<const float4*>(price + j * R_ + r0 + rq);
        prT[rq + 0][j] = p4.x;
        prT[rq + 1][j] = p4.y;
        prT[rq + 2][j] = p4.z;
        prT[rq + 3][j] = p4.w;
    }
    __syncthreads();

    // ---- per-row compute: 16 lanes own one row ----
    const int w    = t >> 6;        // wave 0..7
    const int l    = t & 63;
    const int sub  = l >> 4;        // 0..3  (row within wave)
    const int g    = l & 15;        // 0..15 (j-group within row)
    const int rloc = w * 4 + sub;   // 0..31
    const int row  = r0 + rloc;

    // per-row scalars (redundant across the 16 lanes; broadcast loads)
    const float np_  = need_prev[row];
    const float padp = pool_adp[row];
    const float patp = pool_atp[row];
    const float pamp = pool_amp[row];
    const float gr   = greed[row];

    const float recharge = fminf(padp, np_ * DT_);
    const float atp = patp + recharge;
    const float adp = padp - recharge;
    const float aec = (atp + 0.5f * adp) / (atp + adp + pamp + EPS_);

    const float f1 = fminf(fmaxf(bases[1] + scales[1] * gr, 0.0f), 0.9f);
    const float f2 = fminf(fmaxf(bases[2] + scales[2] * gr, 0.0f), 0.9f);
    const float wealth = atp;
    const float innov_budget = wealth * f1 * (1.0f / (float)J_);
    float atp_book = atp - wealth * (f1 + f2);

    // ---- M-dim partial: q.sum ----
    float qpart;
    {
        const float2 e2 = *reinterpret_cast<const float2*>(extraction_eff + row * M_ + g * 2);
        const float2 d2 = *reinterpret_cast<const float2*>(deposits       + row * M_ + g * 2);
        qpart = (e2.x * d2.x + e2.y * d2.y) * DT_;
    }

    // ---- J-dim partials: rate.sum and (rate*price).sum ----
    const float4 iv  = *reinterpret_cast<const float4*>(inventory  + row * J_ + g * 4);
    const float4 en  = *reinterpret_cast<const float4*>(endowment  + row * J_ + g * 4);
    const float4 inn = *reinterpret_cast<const float4*>(innovation + row * J_ + g * 4);

    float rpart = 0.0f, rppart = 0.0f;
    #pragma unroll
    for (int k = 0; k < 4; ++k) {
        const float invv = (&iv.x)[k];
        const float endv = (&en.x)[k];
        const float inno = (&inn.x)[k];
        const float inv1 = fmaxf(invv + DT_ * endv, 0.0f);
        const float innov_new = inno + DT_ * 0.05f * innov_budget / (1.0f + inno);
        const float rate = 0.1f * DT_ * innov_new * inv1 * aec;
        rpart  += rate;
        rppart += rate * prT[rloc][g * 4 + k];
    }

    // ---- reduce across the 16 lanes of this row (xor 1,2,4,8 stays in-group) ----
    float qsum = qpart, rsum = rpart, rpsum = rppart;
    #pragma unroll
    for (int off = 1; off < 16; off <<= 1) {
        qsum  += __shfl_xor(qsum,  off);
        rsum  += __shfl_xor(rsum,  off);
        rpsum += __shfl_xor(rpsum, off);
    }

    // ---- sequential scalar chain ----
    const float cost  = qsum * 0.5f;
    const float scale = fminf(fmaxf(atp_book / (cost + EPS_), 0.0f), 1.0f);
    const float qs    = qsum * scale;
    atp_book -= scale * cost;

    const float pcost  = rsum * 0.3f;
    const float pscale = fminf(fmaxf(atp_book / (pcost + EPS_), 0.0f), 1.0f);

    const float ex_new = fminf(fmaxf(exergy_price[row] * (1.0f + 0.02f * (0.5f - aec)),
                                     1e-4f), 1e4f);

    if (g == 0) {
        out[row]       = pscale * rpsum + qs * ex_new;
        out[R_ + row]  = aec;
    }
}

} // namespace

extern "C" void kernel_launch(void* const* d_in, const int* in_sizes, int n_in,
                              void* d_out, int out_size, void* d_ws, size_t ws_size,
                              hipStream_t stream) {
    const float* need_prev      = (const float*)d_in[0];
    const float* inventory      = (const float*)d_in[1];
    const float* endowment      = (const float*)d_in[2];
    const float* price          = (const float*)d_in[3];
    const float* pool_atp       = (const float*)d_in[4];
    const float* pool_adp       = (const float*)d_in[5];
    const float* pool_amp       = (const float*)d_in[6];
    // d_in[7] population — unused (not needed for gdp/aec)
    const float* greed          = (const float*)d_in[8];
    const float* innovation     = (const float*)d_in[9];
    const float* extraction_eff = (const float*)d_in[10];
    const float* deposits       = (const float*)d_in[11];
    // d_in[12] emit_sink, d_in[13] sink_state, d_in[14] sink_price — unused
    const float* exergy_price   = (const float*)d_in[15];
    // d_in[16] storage_cap — unused
    const float* bases          = (const float*)d_in[17];
    const float* scales         = (const float*)d_in[18];

    float* out = (float*)d_out;

    const int grid = R_ / ROWS;   // 4096 blocks
    econ_kernel<<<grid, THREADS, 0, stream>>>(
        need_prev, inventory, endowment, price,
        pool_atp, pool_adp, pool_amp, greed,
        innovation, extraction_eff, deposits,
        exergy_price, bases, scales, out);
}